// Round 1
// baseline (4622.543 us; speedup 1.0000x reference)
//
#include <hip/hip_runtime.h>
#include <stdint.h>

#define NN 100000
#define NE 1250000
#define DD 64
#define NL 4

// ---- float atomic max via int/uint trick (valid: init = -inf, finite vals) ----
__device__ __forceinline__ void atomicMaxF(float* addr, float val) {
    if (val >= 0.0f) {
        atomicMax((int*)addr, __float_as_int(val));
    } else {
        atomicMin((unsigned int*)addr, __float_as_uint(val));
    }
}

// ---- init agg to -inf bit pattern ----
__global__ __launch_bounds__(256) void init_agg_kernel(uint32_t* __restrict__ agg) {
    int i = blockIdx.x * 256 + threadIdx.x;            // one uint4 per thread
    uint4 v = make_uint4(0xFF800000u, 0xFF800000u, 0xFF800000u, 0xFF800000u);
    ((uint4*)agg)[i] = v;                              // NN*DD divisible by 4*256
}

// ---- scatter max: 16 threads per edge, 4 floats each ----
__global__ __launch_bounds__(256) void scatter_max_kernel(
        const float* __restrict__ h,
        const int*   __restrict__ src,
        const int*   __restrict__ dst,
        float*       __restrict__ agg) {
    long long t = (long long)blockIdx.x * 256 + threadIdx.x;
    int e = (int)(t >> 4);
    if (e >= NE) return;
    int r = ((int)t & 15) * 4;
    int s = src[e];
    int d = dst[e];
    float4 v = *(const float4*)(h + (size_t)s * DD + r);
    float* a = agg + (size_t)d * DD + r;
    atomicMaxF(a + 0, v.x);
    atomicMaxF(a + 1, v.y);
    atomicMaxF(a + 2, v.z);
    atomicMaxF(a + 3, v.w);
}

// ---- per-layer dense update: h = relu(clean(agg) @ Wl + bl + h @ Wr), in place ----
// 256 threads = 4 nodes x 64 cols per block. Weights staged in LDS.
__global__ __launch_bounds__(256) void layer_kernel(
        const float* __restrict__ agg,
        float*       __restrict__ h,      // read + write in place
        const float* __restrict__ Wl,     // [64][64] row-major (k, j)
        const float* __restrict__ bl,     // [64]
        const float* __restrict__ Wr) {   // [64][64]
    __shared__ float wl_s[DD * DD];
    __shared__ float wr_s[DD * DD];
    __shared__ float bl_s[DD];
    __shared__ float a_s[4][DD];
    __shared__ float h_s[4][DD];

    int tid = threadIdx.x;
    // stage weights
    #pragma unroll
    for (int k = 0; k < 16; ++k) {
        wl_s[tid + k * 256] = Wl[tid + k * 256];
        wr_s[tid + k * 256] = Wr[tid + k * 256];
    }
    if (tid < DD) bl_s[tid] = bl[tid];

    int nl = tid >> 6;          // 0..3 local node
    int j  = tid & 63;          // output column
    int n  = blockIdx.x * 4 + nl;  // NN = 25000*4 exactly

    // stage this block's agg / h rows (clean -inf -> 0 on load)
    float av = agg[(size_t)n * DD + j];
    if (__float_as_uint(av) == 0xFF800000u) av = 0.0f;
    a_s[nl][j] = av;
    h_s[nl][j] = h[(size_t)n * DD + j];
    __syncthreads();

    float acc = bl_s[j];
    #pragma unroll
    for (int k = 0; k < DD; ++k) {
        acc += a_s[nl][k] * wl_s[k * DD + j];
        acc += h_s[nl][k] * wr_s[k * DD + j];
    }
    acc = fmaxf(acc, 0.0f);
    h[(size_t)n * DD + j] = acc;
}

extern "C" void kernel_launch(void* const* d_in, const int* in_sizes, int n_in,
                              void* d_out, int out_size, void* d_ws, size_t ws_size,
                              hipStream_t stream) {
    const float* x    = (const float*)d_in[0];
    const int*   ei   = (const int*)d_in[1];     // [2][NE], int32 (jax x64 disabled)
    const float* Wl   = (const float*)d_in[2];   // [4][64][64]
    const float* bl   = (const float*)d_in[3];   // [4][64]
    const float* Wr   = (const float*)d_in[4];   // [4][64][64]
    float* h   = (float*)d_out;                  // h lives in d_out, updated in place
    float* agg = (float*)d_ws;                   // 25.6 MB scratch

    const int* src = ei;            // row 0
    const int* dst = ei + NE;       // row 1

    // h = x
    hipMemcpyAsync(h, x, (size_t)NN * DD * sizeof(float),
                   hipMemcpyDeviceToDevice, stream);

    const int initBlocks    = (NN * DD / 4) / 256;            // 6250
    const int scatterBlocks = (NE * 16 + 255) / 256;          // 78125
    const int layerBlocks   = NN / 4;                          // 25000

    for (int l = 0; l < NL; ++l) {
        init_agg_kernel<<<initBlocks, 256, 0, stream>>>((uint32_t*)agg);
        scatter_max_kernel<<<scatterBlocks, 256, 0, stream>>>(h, src, dst, agg);
        layer_kernel<<<layerBlocks, 256, 0, stream>>>(
            agg, h, Wl + (size_t)l * DD * DD, bl + (size_t)l * DD, Wr + (size_t)l * DD * DD);
    }
}

// Round 2
// 803.358 us; speedup vs baseline: 5.7540x; 5.7540x over previous
//
#include <hip/hip_runtime.h>
#include <stdint.h>

#define NN 100000
#define NE 1250000
#define DD 64
#define NL 4
#define SCAN_B 1024
#define SCAN_NB ((NN + SCAN_B - 1) / SCAN_B)   // 98

// ---------------- CSR build ----------------

__global__ __launch_bounds__(256) void hist_kernel(const int* __restrict__ dst,
                                                   int* __restrict__ deg) {
    int e = blockIdx.x * 256 + threadIdx.x;
    if (e < NE) atomicAdd(&deg[dst[e]], 1);
}

__global__ __launch_bounds__(SCAN_B) void scan1_kernel(const int* __restrict__ deg,
                                                       int* __restrict__ row_start,
                                                       int* __restrict__ blocksums) {
    __shared__ int sm[SCAN_B];
    int tid = threadIdx.x;
    int i = blockIdx.x * SCAN_B + tid;
    int d = (i < NN) ? deg[i] : 0;
    sm[tid] = d;
    __syncthreads();
    for (int off = 1; off < SCAN_B; off <<= 1) {
        int v = (tid >= off) ? sm[tid - off] : 0;
        __syncthreads();
        sm[tid] += v;
        __syncthreads();
    }
    if (i < NN) row_start[i] = sm[tid] - d;       // exclusive within block
    if (tid == SCAN_B - 1) blocksums[blockIdx.x] = sm[tid];
}

__global__ void scan2_kernel(int* __restrict__ blocksums) {
    if (threadIdx.x == 0 && blockIdx.x == 0) {
        int running = 0;
        for (int b = 0; b < SCAN_NB; ++b) {
            int t = blocksums[b];
            blocksums[b] = running;
            running += t;
        }
    }
}

__global__ __launch_bounds__(SCAN_B) void scan3_kernel(int* __restrict__ row_start,
                                                       const int* __restrict__ blocksums) {
    int i = blockIdx.x * SCAN_B + threadIdx.x;
    if (i < NN) row_start[i] += blocksums[blockIdx.x];
}

__global__ __launch_bounds__(256) void fill_kernel(const int* __restrict__ src,
                                                   const int* __restrict__ dst,
                                                   const int* __restrict__ row_start,
                                                   int* __restrict__ cursor,
                                                   int* __restrict__ csr) {
    int e = blockIdx.x * 256 + threadIdx.x;
    if (e < NE) {
        int d = dst[e];
        int pos = atomicAdd(&cursor[d], 1);
        csr[row_start[d] + pos] = src[e];
    }
}

// ---------------- per-layer gather-max aggregation ----------------
// block = 256 threads = 4 waves; one wave per node, lane j = column j.
__global__ __launch_bounds__(256) void agg_kernel(const float* __restrict__ h,
                                                  const int* __restrict__ row_start,
                                                  const int* __restrict__ deg,
                                                  const int* __restrict__ csr,
                                                  float* __restrict__ agg) {
    int tid = threadIdx.x;
    int nl = tid >> 6;
    int j = tid & 63;
    int n = blockIdx.x * 4 + nl;          // NN = 25000*4 exactly
    int base = row_start[n];
    int cnt = deg[n];

    float acc = -__builtin_huge_valf();
    int k = 0;
    for (; k + 4 <= cnt; k += 4) {
        int s0 = csr[base + k + 0];
        int s1 = csr[base + k + 1];
        int s2 = csr[base + k + 2];
        int s3 = csr[base + k + 3];
        float v0 = h[s0 * DD + j];
        float v1 = h[s1 * DD + j];
        float v2 = h[s2 * DD + j];
        float v3 = h[s3 * DD + j];
        acc = fmaxf(acc, fmaxf(fmaxf(v0, v1), fmaxf(v2, v3)));
    }
    for (; k < cnt; ++k) {
        int s = csr[base + k];
        acc = fmaxf(acc, h[s * DD + j]);
    }
    agg[(size_t)n * DD + j] = (cnt == 0) ? 0.0f : acc;   // PyG empty-segment -> 0
}

// ---------------- dense update: h = relu(agg @ Wl + bl + h @ Wr), in place ----------------
__global__ __launch_bounds__(256) void layer_kernel(const float* __restrict__ agg,
                                                    float* __restrict__ h,
                                                    const float* __restrict__ Wl,
                                                    const float* __restrict__ bl,
                                                    const float* __restrict__ Wr) {
    __shared__ float wl_s[DD * DD];
    __shared__ float wr_s[DD * DD];
    __shared__ float bl_s[DD];
    __shared__ float a_s[4][DD];
    __shared__ float h_s[4][DD];

    int tid = threadIdx.x;
    #pragma unroll
    for (int k = 0; k < 16; ++k) {
        wl_s[tid + k * 256] = Wl[tid + k * 256];
        wr_s[tid + k * 256] = Wr[tid + k * 256];
    }
    if (tid < DD) bl_s[tid] = bl[tid];

    int nl = tid >> 6;
    int j = tid & 63;
    int n = blockIdx.x * 4 + nl;

    a_s[nl][j] = agg[(size_t)n * DD + j];
    h_s[nl][j] = h[(size_t)n * DD + j];
    __syncthreads();

    float acc = bl_s[j];
    #pragma unroll
    for (int k = 0; k < DD; ++k) {
        acc += a_s[nl][k] * wl_s[k * DD + j];
        acc += h_s[nl][k] * wr_s[k * DD + j];
    }
    acc = fmaxf(acc, 0.0f);
    h[(size_t)n * DD + j] = acc;
}

extern "C" void kernel_launch(void* const* d_in, const int* in_sizes, int n_in,
                              void* d_out, int out_size, void* d_ws, size_t ws_size,
                              hipStream_t stream) {
    const float* x  = (const float*)d_in[0];
    const int*   ei = (const int*)d_in[1];
    const float* Wl = (const float*)d_in[2];
    const float* bl = (const float*)d_in[3];
    const float* Wr = (const float*)d_in[4];
    float* h = (float*)d_out;

    const int* src = ei;
    const int* dst = ei + NE;

    // ---- workspace layout ----
    char* ws = (char*)d_ws;
    float* agg       = (float*)ws;                 ws += (size_t)NN * DD * sizeof(float); // 25.6 MB
    int*   row_start = (int*)ws;                   ws += (size_t)NN * sizeof(int);
    int*   deg       = (int*)ws;                   ws += (size_t)NN * sizeof(int);
    int*   cursor    = (int*)ws;                   ws += (size_t)NN * sizeof(int);
    int*   blocksums = (int*)ws;                   ws += (size_t)SCAN_NB * sizeof(int);
    int*   csr       = (int*)ws;                   // NE ints = 5 MB

    // h = x
    hipMemcpyAsync(h, x, (size_t)NN * DD * sizeof(float), hipMemcpyDeviceToDevice, stream);

    // ---- CSR build (edge list is static; rebuilt every call for capture-safety) ----
    hipMemsetAsync(deg, 0, (size_t)NN * sizeof(int), stream);
    hipMemsetAsync(cursor, 0, (size_t)NN * sizeof(int), stream);
    hist_kernel<<<(NE + 255) / 256, 256, 0, stream>>>(dst, deg);
    scan1_kernel<<<SCAN_NB, SCAN_B, 0, stream>>>(deg, row_start, blocksums);
    scan2_kernel<<<1, 64, 0, stream>>>(blocksums);
    scan3_kernel<<<SCAN_NB, SCAN_B, 0, stream>>>(row_start, blocksums);
    fill_kernel<<<(NE + 255) / 256, 256, 0, stream>>>(src, dst, row_start, cursor, csr);

    // ---- layers ----
    for (int l = 0; l < NL; ++l) {
        agg_kernel<<<NN / 4, 256, 0, stream>>>(h, row_start, deg, csr, agg);
        layer_kernel<<<NN / 4, 256, 0, stream>>>(
            agg, h, Wl + (size_t)l * DD * DD, bl + (size_t)l * DD, Wr + (size_t)l * DD * DD);
    }
}

// Round 3
// 543.062 us; speedup vs baseline: 8.5120x; 1.4793x over previous
//
#include <hip/hip_runtime.h>
#include <stdint.h>

#define NN 100000
#define NE 1250000
#define DD 64
#define NL 4
#define SCAN_B 1024
#define SCAN_NB ((NN + SCAN_B - 1) / SCAN_B)   // 98

#define MB 256               // nodes per layer-GEMM block
#define KT 32                // k-tile
#define ASTRIDE 260          // a_t row stride in floats (multiple of 4, breaks pow2)
#define LBLOCKS ((NN + MB - 1) / MB)   // 391

// ---------------- CSR build ----------------

__global__ __launch_bounds__(256) void hist_kernel(const int* __restrict__ dst,
                                                   int* __restrict__ deg) {
    int e = blockIdx.x * 256 + threadIdx.x;
    if (e < NE) atomicAdd(&deg[dst[e]], 1);
}

__global__ __launch_bounds__(SCAN_B) void scan1_kernel(const int* __restrict__ deg,
                                                       int* __restrict__ row_start,
                                                       int* __restrict__ blocksums) {
    __shared__ int sm[SCAN_B];
    int tid = threadIdx.x;
    int i = blockIdx.x * SCAN_B + tid;
    int d = (i < NN) ? deg[i] : 0;
    sm[tid] = d;
    __syncthreads();
    for (int off = 1; off < SCAN_B; off <<= 1) {
        int v = (tid >= off) ? sm[tid - off] : 0;
        __syncthreads();
        sm[tid] += v;
        __syncthreads();
    }
    if (i < NN) row_start[i] = sm[tid] - d;
    if (tid == SCAN_B - 1) blocksums[blockIdx.x] = sm[tid];
}

__global__ void scan2_kernel(int* __restrict__ blocksums) {
    if (threadIdx.x == 0 && blockIdx.x == 0) {
        int running = 0;
        for (int b = 0; b < SCAN_NB; ++b) {
            int t = blocksums[b];
            blocksums[b] = running;
            running += t;
        }
    }
}

__global__ __launch_bounds__(SCAN_B) void scan3_kernel(int* __restrict__ row_start,
                                                       const int* __restrict__ blocksums) {
    int i = blockIdx.x * SCAN_B + threadIdx.x;
    if (i < NN) row_start[i] += blocksums[blockIdx.x];
}

__global__ __launch_bounds__(256) void fill_kernel(const int* __restrict__ src,
                                                   const int* __restrict__ dst,
                                                   const int* __restrict__ row_start,
                                                   int* __restrict__ cursor,
                                                   int* __restrict__ csr) {
    int e = blockIdx.x * 256 + threadIdx.x;
    if (e < NE) {
        int d = dst[e];
        int pos = atomicAdd(&cursor[d], 1);
        csr[row_start[d] + pos] = src[e];
    }
}

// ---------------- per-layer gather-max aggregation ----------------
// one wave per node, lane j = column j; unroll 8 for loads in flight.
__global__ __launch_bounds__(256) void agg_kernel(const float* __restrict__ h,
                                                  const int* __restrict__ row_start,
                                                  const int* __restrict__ deg,
                                                  const int* __restrict__ csr,
                                                  float* __restrict__ agg) {
    int tid = threadIdx.x;
    int nl = tid >> 6;
    int j = tid & 63;
    int n = blockIdx.x * 4 + nl;          // NN = 25000*4 exactly
    int base = row_start[n];
    int cnt = deg[n];

    float acc = -__builtin_huge_valf();
    int k = 0;
    for (; k + 8 <= cnt; k += 8) {
        int s0 = csr[base + k + 0];
        int s1 = csr[base + k + 1];
        int s2 = csr[base + k + 2];
        int s3 = csr[base + k + 3];
        int s4 = csr[base + k + 4];
        int s5 = csr[base + k + 5];
        int s6 = csr[base + k + 6];
        int s7 = csr[base + k + 7];
        float v0 = h[s0 * DD + j];
        float v1 = h[s1 * DD + j];
        float v2 = h[s2 * DD + j];
        float v3 = h[s3 * DD + j];
        float v4 = h[s4 * DD + j];
        float v5 = h[s5 * DD + j];
        float v6 = h[s6 * DD + j];
        float v7 = h[s7 * DD + j];
        float m0 = fmaxf(fmaxf(v0, v1), fmaxf(v2, v3));
        float m1 = fmaxf(fmaxf(v4, v5), fmaxf(v6, v7));
        acc = fmaxf(acc, fmaxf(m0, m1));
    }
    for (; k < cnt; ++k) {
        int s = csr[base + k];
        acc = fmaxf(acc, h[s * DD + j]);
    }
    agg[(size_t)n * DD + j] = (cnt == 0) ? 0.0f : acc;
}

// ---------------- dense update: h = relu(agg @ Wl + bl + h @ Wr), in place ----
// 256 threads; per-thread 8 nodes x 8 outputs register tile; A staged transposed.
__global__ __launch_bounds__(256, 2) void layer_kernel(const float* __restrict__ agg,
                                                       float* __restrict__ h,
                                                       const float* __restrict__ Wl,
                                                       const float* __restrict__ bl,
                                                       const float* __restrict__ Wr) {
    __shared__ float w_s[128 * DD];          // 32 KB: rows 0..63 = Wl, 64..127 = Wr
    __shared__ float a_t[KT * ASTRIDE];      // 33.3 KB: transposed k-tile of [agg|h]

    int tid = threadIdx.x;
    int mg = tid >> 3;        // 0..31 : node-group of 8
    int jg = tid & 7;         // 0..7  : output-group of 8
    int node0 = blockIdx.x * MB;

    // stage W: 8192 floats, 8 float4 per thread
    #pragma unroll
    for (int r = 0; r < 8; ++r) {
        int idx = r * 256 + tid;          // float4 index 0..2047
        int k = idx >> 4;                 // 0..127
        int j4 = (idx & 15) * 4;
        const float* wsrc = (k < 64) ? (Wl + k * DD + j4) : (Wr + (k - 64) * DD + j4);
        *(float4*)&w_s[k * DD + j4] = *(const float4*)wsrc;
    }

    float acc[8][8];
    #pragma unroll
    for (int mi = 0; mi < 8; ++mi)
        #pragma unroll
        for (int ji = 0; ji < 8; ++ji) acc[mi][ji] = 0.0f;

    #pragma unroll
    for (int t = 0; t < 4; ++t) {
        __syncthreads();
        // stage A tile transposed: source = agg (t<2) else h; cols (t&1)*32 .. +31
        const float* smat = (t < 2) ? agg : h;
        int kbase = (t & 1) * KT;
        #pragma unroll
        for (int r = 0; r < 8; ++r) {
            int idx = r * 256 + tid;          // 0..2047 float4s
            int ml = idx >> 3;                // 0..255 local node
            int k4 = (idx & 7) * 4;           // 0..28
            int node = node0 + ml;
            if (node > NN - 1) node = NN - 1;
            float4 v = *(const float4*)&smat[(size_t)node * DD + kbase + k4];
            a_t[(k4 + 0) * ASTRIDE + ml] = v.x;
            a_t[(k4 + 1) * ASTRIDE + ml] = v.y;
            a_t[(k4 + 2) * ASTRIDE + ml] = v.z;
            a_t[(k4 + 3) * ASTRIDE + ml] = v.w;
        }
        __syncthreads();

        #pragma unroll 2
        for (int kk = 0; kk < KT; ++kk) {
            float4 av0 = *(const float4*)&a_t[kk * ASTRIDE + mg * 8];
            float4 av1 = *(const float4*)&a_t[kk * ASTRIDE + mg * 8 + 4];
            float4 wv0 = *(const float4*)&w_s[(t * KT + kk) * DD + jg * 8];
            float4 wv1 = *(const float4*)&w_s[(t * KT + kk) * DD + jg * 8 + 4];
            float am[8] = {av0.x, av0.y, av0.z, av0.w, av1.x, av1.y, av1.z, av1.w};
            float wj[8] = {wv0.x, wv0.y, wv0.z, wv0.w, wv1.x, wv1.y, wv1.z, wv1.w};
            #pragma unroll
            for (int mi = 0; mi < 8; ++mi)
                #pragma unroll
                for (int ji = 0; ji < 8; ++ji)
                    acc[mi][ji] += am[mi] * wj[ji];
        }
    }

    // epilogue: + bias, relu, store
    float bj[8];
    #pragma unroll
    for (int ji = 0; ji < 8; ++ji) bj[ji] = bl[jg * 8 + ji];

    #pragma unroll
    for (int mi = 0; mi < 8; ++mi) {
        int node = node0 + mg * 8 + mi;
        if (node < NN) {
            float4 o0, o1;
            o0.x = fmaxf(acc[mi][0] + bj[0], 0.0f);
            o0.y = fmaxf(acc[mi][1] + bj[1], 0.0f);
            o0.z = fmaxf(acc[mi][2] + bj[2], 0.0f);
            o0.w = fmaxf(acc[mi][3] + bj[3], 0.0f);
            o1.x = fmaxf(acc[mi][4] + bj[4], 0.0f);
            o1.y = fmaxf(acc[mi][5] + bj[5], 0.0f);
            o1.z = fmaxf(acc[mi][6] + bj[6], 0.0f);
            o1.w = fmaxf(acc[mi][7] + bj[7], 0.0f);
            *(float4*)&h[(size_t)node * DD + jg * 8] = o0;
            *(float4*)&h[(size_t)node * DD + jg * 8 + 4] = o1;
        }
    }
}

extern "C" void kernel_launch(void* const* d_in, const int* in_sizes, int n_in,
                              void* d_out, int out_size, void* d_ws, size_t ws_size,
                              hipStream_t stream) {
    const float* x  = (const float*)d_in[0];
    const int*   ei = (const int*)d_in[1];
    const float* Wl = (const float*)d_in[2];
    const float* bl = (const float*)d_in[3];
    const float* Wr = (const float*)d_in[4];
    float* h = (float*)d_out;

    const int* src = ei;
    const int* dst = ei + NE;

    char* ws = (char*)d_ws;
    float* agg       = (float*)ws;                 ws += (size_t)NN * DD * sizeof(float);
    int*   row_start = (int*)ws;                   ws += (size_t)NN * sizeof(int);
    int*   deg       = (int*)ws;                   ws += (size_t)NN * sizeof(int);
    int*   cursor    = (int*)ws;                   ws += (size_t)NN * sizeof(int);
    int*   blocksums = (int*)ws;                   ws += (size_t)SCAN_NB * sizeof(int);
    int*   csr       = (int*)ws;

    hipMemcpyAsync(h, x, (size_t)NN * DD * sizeof(float), hipMemcpyDeviceToDevice, stream);

    hipMemsetAsync(deg, 0, (size_t)NN * sizeof(int), stream);
    hipMemsetAsync(cursor, 0, (size_t)NN * sizeof(int), stream);
    hist_kernel<<<(NE + 255) / 256, 256, 0, stream>>>(dst, deg);
    scan1_kernel<<<SCAN_NB, SCAN_B, 0, stream>>>(deg, row_start, blocksums);
    scan2_kernel<<<1, 64, 0, stream>>>(blocksums);
    scan3_kernel<<<SCAN_NB, SCAN_B, 0, stream>>>(row_start, blocksums);
    fill_kernel<<<(NE + 255) / 256, 256, 0, stream>>>(src, dst, row_start, cursor, csr);

    for (int l = 0; l < NL; ++l) {
        agg_kernel<<<NN / 4, 256, 0, stream>>>(h, row_start, deg, csr, agg);
        layer_kernel<<<LBLOCKS, 256, 0, stream>>>(
            agg, h, Wl + (size_t)l * DD * DD, bl + (size_t)l * DD, Wr + (size_t)l * DD * DD);
    }
}

// Round 4
// 525.575 us; speedup vs baseline: 8.7952x; 1.0333x over previous
//
#include <hip/hip_runtime.h>
#include <stdint.h>

#define NN 100000
#define NE 1250000
#define DD 64
#define NL 4
#define SCAN_B 1024
#define SCAN_NB ((NN + SCAN_B - 1) / SCAN_B)   // 98

#define MB 128               // nodes per layer-GEMM block
#define KT 32                // k-tile
#define ASTRIDE 132          // a_t row stride (multiple of 4, breaks pow2)
#define LBLOCKS ((NN + MB - 1) / MB)   // 782

// ---------------- CSR build ----------------

__global__ __launch_bounds__(256) void hist_kernel(const int* __restrict__ dst,
                                                   int* __restrict__ deg) {
    int i = blockIdx.x * 256 + threadIdx.x;
    if (i < NE / 4) {                       // NE divisible by 4
        int4 d = ((const int4*)dst)[i];
        atomicAdd(&deg[d.x], 1);
        atomicAdd(&deg[d.y], 1);
        atomicAdd(&deg[d.z], 1);
        atomicAdd(&deg[d.w], 1);
    }
}

__global__ __launch_bounds__(SCAN_B) void scan1_kernel(const int* __restrict__ deg,
                                                       int* __restrict__ row_start,
                                                       int* __restrict__ blocksums) {
    __shared__ int sm[SCAN_B];
    int tid = threadIdx.x;
    int i = blockIdx.x * SCAN_B + tid;
    int d = (i < NN) ? deg[i] : 0;
    sm[tid] = d;
    __syncthreads();
    for (int off = 1; off < SCAN_B; off <<= 1) {
        int v = (tid >= off) ? sm[tid - off] : 0;
        __syncthreads();
        sm[tid] += v;
        __syncthreads();
    }
    if (i < NN) row_start[i] = sm[tid] - d;
    if (tid == SCAN_B - 1) blocksums[blockIdx.x] = sm[tid];
}

// parallel LDS scan over the 98 block sums (was a serial 98-step loop)
__global__ __launch_bounds__(128) void scan2_kernel(int* __restrict__ blocksums) {
    __shared__ int sm[128];
    int tid = threadIdx.x;
    int v = (tid < SCAN_NB) ? blocksums[tid] : 0;
    sm[tid] = v;
    __syncthreads();
    for (int off = 1; off < 128; off <<= 1) {
        int t = (tid >= off) ? sm[tid - off] : 0;
        __syncthreads();
        sm[tid] += t;
        __syncthreads();
    }
    if (tid < SCAN_NB) blocksums[tid] = sm[tid] - v;   // exclusive
}

__global__ __launch_bounds__(SCAN_B) void scan3_kernel(int* __restrict__ row_start,
                                                       const int* __restrict__ blocksums) {
    int i = blockIdx.x * SCAN_B + threadIdx.x;
    if (i < NN) row_start[i] += blocksums[blockIdx.x];
}

__global__ __launch_bounds__(256) void fill_kernel(const int* __restrict__ src,
                                                   const int* __restrict__ dst,
                                                   const int* __restrict__ row_start,
                                                   int* __restrict__ cursor,
                                                   int* __restrict__ csr) {
    int i = blockIdx.x * 256 + threadIdx.x;
    if (i < NE / 4) {
        int4 s = ((const int4*)src)[i];
        int4 d = ((const int4*)dst)[i];
        int p;
        p = atomicAdd(&cursor[d.x], 1); csr[row_start[d.x] + p] = s.x;
        p = atomicAdd(&cursor[d.y], 1); csr[row_start[d.y] + p] = s.y;
        p = atomicAdd(&cursor[d.z], 1); csr[row_start[d.z] + p] = s.z;
        p = atomicAdd(&cursor[d.w], 1); csr[row_start[d.w] + p] = s.w;
    }
}

// ---------------- per-layer gather-max aggregation ----------------
// one wave per node; 16 lanes x float4 = one 256B row, so 4 neighbor rows per
// wave-instruction; unroll 2 -> 8 rows in flight. Tail via index clamp (max is
// idempotent). Final reduce across the 4 lane-groups via shfl_xor 16/32.
__global__ __launch_bounds__(256) void agg_kernel(const float* __restrict__ h,
                                                  const int* __restrict__ row_start,
                                                  const int* __restrict__ deg,
                                                  const int* __restrict__ csr,
                                                  float* __restrict__ agg) {
    int tid = threadIdx.x;
    int wv = tid >> 6;
    int lane = tid & 63;
    int g = lane >> 4;              // neighbor sub-slot 0..3
    int c4 = (lane & 15) * 4;       // column base
    int n = blockIdx.x * 4 + wv;    // NN = 25000*4 exactly
    int base = row_start[n];
    int cnt = deg[n];

    float4 acc;
    if (cnt > 0) {
        const float NI = -__builtin_huge_valf();
        acc = make_float4(NI, NI, NI, NI);
        int last = cnt - 1;
        for (int k = 0; k < cnt; k += 8) {
            int k0 = k + g;     if (k0 > last) k0 = last;
            int k1 = k + g + 4; if (k1 > last) k1 = last;
            int s0 = csr[base + k0];
            int s1 = csr[base + k1];
            float4 v0 = *(const float4*)&h[(size_t)s0 * DD + c4];
            float4 v1 = *(const float4*)&h[(size_t)s1 * DD + c4];
            acc.x = fmaxf(acc.x, fmaxf(v0.x, v1.x));
            acc.y = fmaxf(acc.y, fmaxf(v0.y, v1.y));
            acc.z = fmaxf(acc.z, fmaxf(v0.z, v1.z));
            acc.w = fmaxf(acc.w, fmaxf(v0.w, v1.w));
        }
        acc.x = fmaxf(acc.x, __shfl_xor(acc.x, 16, 64));
        acc.y = fmaxf(acc.y, __shfl_xor(acc.y, 16, 64));
        acc.z = fmaxf(acc.z, __shfl_xor(acc.z, 16, 64));
        acc.w = fmaxf(acc.w, __shfl_xor(acc.w, 16, 64));
        acc.x = fmaxf(acc.x, __shfl_xor(acc.x, 32, 64));
        acc.y = fmaxf(acc.y, __shfl_xor(acc.y, 32, 64));
        acc.z = fmaxf(acc.z, __shfl_xor(acc.z, 32, 64));
        acc.w = fmaxf(acc.w, __shfl_xor(acc.w, 32, 64));
    } else {
        acc = make_float4(0.f, 0.f, 0.f, 0.f);   // PyG empty-segment -> 0
    }
    if (lane < 16) *(float4*)&agg[(size_t)n * DD + c4] = acc;
}

// ---------------- dense update: h = relu(agg @ Wl + bl + h @ Wr), in place ----
// 256 threads; 128 nodes/block (782 blocks -> ~3/CU); per-thread 4 nodes x 8
// outputs; A staged transposed in LDS. LDS = 48.5 KB.
__global__ __launch_bounds__(256, 2) void layer_kernel(const float* __restrict__ agg,
                                                       float* __restrict__ h,
                                                       const float* __restrict__ Wl,
                                                       const float* __restrict__ bl,
                                                       const float* __restrict__ Wr) {
    __shared__ float w_s[128 * DD];          // 32 KB: rows 0..63 = Wl, 64..127 = Wr
    __shared__ float a_t[KT * ASTRIDE];      // 16.5 KB: transposed k-tile of [agg|h]

    int tid = threadIdx.x;
    int ng = tid >> 3;        // 0..31 : node-group of 4
    int jg = tid & 7;         // 0..7  : output-group of 8
    int node0 = blockIdx.x * MB;

    // stage W: 8192 floats, 8 float4 per thread
    #pragma unroll
    for (int r = 0; r < 8; ++r) {
        int idx = r * 256 + tid;
        int k = idx >> 4;
        int j4 = (idx & 15) * 4;
        const float* wsrc = (k < 64) ? (Wl + k * DD + j4) : (Wr + (k - 64) * DD + j4);
        *(float4*)&w_s[k * DD + j4] = *(const float4*)wsrc;
    }

    float acc[4][8];
    #pragma unroll
    for (int mi = 0; mi < 4; ++mi)
        #pragma unroll
        for (int ji = 0; ji < 8; ++ji) acc[mi][ji] = 0.0f;

    #pragma unroll
    for (int t = 0; t < 4; ++t) {
        __syncthreads();
        const float* smat = (t < 2) ? agg : h;
        int kbase = (t & 1) * KT;
        #pragma unroll
        for (int r = 0; r < 4; ++r) {
            int idx = r * 256 + tid;          // 0..1023 float4s
            int ml = idx >> 3;                // 0..127 local node
            int k4 = (idx & 7) * 4;
            int node = node0 + ml;
            if (node > NN - 1) node = NN - 1;
            float4 v = *(const float4*)&smat[(size_t)node * DD + kbase + k4];
            a_t[(k4 + 0) * ASTRIDE + ml] = v.x;
            a_t[(k4 + 1) * ASTRIDE + ml] = v.y;
            a_t[(k4 + 2) * ASTRIDE + ml] = v.z;
            a_t[(k4 + 3) * ASTRIDE + ml] = v.w;
        }
        __syncthreads();

        #pragma unroll 4
        for (int kk = 0; kk < KT; ++kk) {
            float4 av  = *(const float4*)&a_t[kk * ASTRIDE + ng * 4];
            float4 wv0 = *(const float4*)&w_s[(t * KT + kk) * DD + jg * 8];
            float4 wv1 = *(const float4*)&w_s[(t * KT + kk) * DD + jg * 8 + 4];
            float am[4] = {av.x, av.y, av.z, av.w};
            float wj[8] = {wv0.x, wv0.y, wv0.z, wv0.w, wv1.x, wv1.y, wv1.z, wv1.w};
            #pragma unroll
            for (int mi = 0; mi < 4; ++mi)
                #pragma unroll
                for (int ji = 0; ji < 8; ++ji)
                    acc[mi][ji] += am[mi] * wj[ji];
        }
    }

    float bj[8];
    #pragma unroll
    for (int ji = 0; ji < 8; ++ji) bj[ji] = bl[jg * 8 + ji];

    #pragma unroll
    for (int mi = 0; mi < 4; ++mi) {
        int node = node0 + ng * 4 + mi;
        if (node < NN) {
            float4 o0, o1;
            o0.x = fmaxf(acc[mi][0] + bj[0], 0.0f);
            o0.y = fmaxf(acc[mi][1] + bj[1], 0.0f);
            o0.z = fmaxf(acc[mi][2] + bj[2], 0.0f);
            o0.w = fmaxf(acc[mi][3] + bj[3], 0.0f);
            o1.x = fmaxf(acc[mi][4] + bj[4], 0.0f);
            o1.y = fmaxf(acc[mi][5] + bj[5], 0.0f);
            o1.z = fmaxf(acc[mi][6] + bj[6], 0.0f);
            o1.w = fmaxf(acc[mi][7] + bj[7], 0.0f);
            *(float4*)&h[(size_t)node * DD + jg * 8] = o0;
            *(float4*)&h[(size_t)node * DD + jg * 8 + 4] = o1;
        }
    }
}

extern "C" void kernel_launch(void* const* d_in, const int* in_sizes, int n_in,
                              void* d_out, int out_size, void* d_ws, size_t ws_size,
                              hipStream_t stream) {
    const float* x  = (const float*)d_in[0];
    const int*   ei = (const int*)d_in[1];
    const float* Wl = (const float*)d_in[2];
    const float* bl = (const float*)d_in[3];
    const float* Wr = (const float*)d_in[4];
    float* h = (float*)d_out;

    const int* src = ei;
    const int* dst = ei + NE;

    char* ws = (char*)d_ws;
    float* agg       = (float*)ws;                 ws += (size_t)NN * DD * sizeof(float);
    int*   row_start = (int*)ws;                   ws += (size_t)NN * sizeof(int);
    int*   deg       = (int*)ws;                   ws += (size_t)NN * sizeof(int);
    int*   cursor    = (int*)ws;                   ws += (size_t)NN * sizeof(int);
    int*   blocksums = (int*)ws;                   ws += (size_t)SCAN_NB * sizeof(int);
    int*   csr       = (int*)ws;

    hipMemcpyAsync(h, x, (size_t)NN * DD * sizeof(float), hipMemcpyDeviceToDevice, stream);

    hipMemsetAsync(deg, 0, (size_t)NN * sizeof(int), stream);
    hipMemsetAsync(cursor, 0, (size_t)NN * sizeof(int), stream);
    hist_kernel<<<(NE / 4 + 255) / 256, 256, 0, stream>>>(dst, deg);
    scan1_kernel<<<SCAN_NB, SCAN_B, 0, stream>>>(deg, row_start, blocksums);
    scan2_kernel<<<1, 128, 0, stream>>>(blocksums);
    scan3_kernel<<<SCAN_NB, SCAN_B, 0, stream>>>(row_start, blocksums);
    fill_kernel<<<(NE / 4 + 255) / 256, 256, 0, stream>>>(src, dst, row_start, cursor, csr);

    for (int l = 0; l < NL; ++l) {
        agg_kernel<<<NN / 4, 256, 0, stream>>>(h, row_start, deg, csr, agg);
        layer_kernel<<<LBLOCKS, 256, 0, stream>>>(
            agg, h, Wl + (size_t)l * DD * DD, bl + (size_t)l * DD, Wr + (size_t)l * DD * DD);
    }
}

// Round 5
// 483.278 us; speedup vs baseline: 9.5650x; 1.0875x over previous
//
#include <hip/hip_runtime.h>
#include <stdint.h>

#define NN 100000
#define NE 1250000
#define DD 64
#define NL 4
#define SCAN_B 1024
#define SCAN_NB ((NN + SCAN_B - 1) / SCAN_B)   // 98

#define MB 128               // nodes per layer-GEMM block
#define KT 32                // k-tile
#define ASTRIDE 132          // a_t row stride (multiple of 4, breaks pow2)
#define LBLOCKS ((NN + MB - 1) / MB)   // 782

#define NPART 8              // XCD partitions for fill
#define PSIZE ((NN + NPART - 1) / NPART)          // 12500 dst nodes per partition
#define FCHUNK 1024          // int4s per fill chunk = 4096 edges
#define NCHUNK ((NE / 4 + FCHUNK - 1) / FCHUNK)   // 306

// ---------------- CSR build ----------------

// histogram + per-edge rank (the atomicAdd return is free — reuse it so the
// fill pass needs no atomics at all)
__global__ __launch_bounds__(256) void hist_kernel(const int* __restrict__ dst,
                                                   int* __restrict__ deg,
                                                   int* __restrict__ rank) {
    int i = blockIdx.x * 256 + threadIdx.x;
    if (i < NE / 4) {
        int4 d = ((const int4*)dst)[i];
        int4 r;
        r.x = atomicAdd(&deg[d.x], 1);
        r.y = atomicAdd(&deg[d.y], 1);
        r.z = atomicAdd(&deg[d.z], 1);
        r.w = atomicAdd(&deg[d.w], 1);
        ((int4*)rank)[i] = r;
    }
}

__global__ __launch_bounds__(SCAN_B) void scan1_kernel(const int* __restrict__ deg,
                                                       int* __restrict__ row_start,
                                                       int* __restrict__ blocksums) {
    __shared__ int sm[SCAN_B];
    int tid = threadIdx.x;
    int i = blockIdx.x * SCAN_B + tid;
    int d = (i < NN) ? deg[i] : 0;
    sm[tid] = d;
    __syncthreads();
    for (int off = 1; off < SCAN_B; off <<= 1) {
        int v = (tid >= off) ? sm[tid - off] : 0;
        __syncthreads();
        sm[tid] += v;
        __syncthreads();
    }
    if (i < NN) row_start[i] = sm[tid] - d;
    if (tid == SCAN_B - 1) blocksums[blockIdx.x] = sm[tid];
}

__global__ __launch_bounds__(128) void scan2_kernel(int* __restrict__ blocksums) {
    __shared__ int sm[128];
    int tid = threadIdx.x;
    int v = (tid < SCAN_NB) ? blocksums[tid] : 0;
    sm[tid] = v;
    __syncthreads();
    for (int off = 1; off < 128; off <<= 1) {
        int t = (tid >= off) ? sm[tid - off] : 0;
        __syncthreads();
        sm[tid] += t;
        __syncthreads();
    }
    if (tid < SCAN_NB) blocksums[tid] = sm[tid] - v;   // exclusive
}

__global__ __launch_bounds__(SCAN_B) void scan3_kernel(int* __restrict__ row_start,
                                                       const int* __restrict__ blocksums) {
    int i = blockIdx.x * SCAN_B + threadIdx.x;
    if (i < NN) row_start[i] += blocksums[blockIdx.x];
}

// atomic-free, XCD-partitioned fill: block b handles only dsts in partition
// (b & 7); consecutive blockIdx round-robin across the 8 XCDs, so each csr
// line is written from (heuristically) one XCD -> no L2 line ping-pong.
// Edge data is re-streamed 8x but served from L2/L3.
__global__ __launch_bounds__(256) void fill_kernel(const int* __restrict__ src,
                                                   const int* __restrict__ dst,
                                                   const int* __restrict__ row_start,
                                                   const int* __restrict__ rank,
                                                   int* __restrict__ csr) {
    int part = blockIdx.x & (NPART - 1);
    int chunk = blockIdx.x >> 3;
    unsigned lo = part * PSIZE;
    int base4 = chunk * FCHUNK;
    #pragma unroll
    for (int r = 0; r < 4; ++r) {
        int i4 = base4 + r * 256 + threadIdx.x;
        if (i4 < NE / 4) {
            int4 d = ((const int4*)dst)[i4];
            int4 s = ((const int4*)src)[i4];
            int4 rk = ((const int4*)rank)[i4];
            if ((unsigned)(d.x - lo) < PSIZE) csr[row_start[d.x] + rk.x] = s.x;
            if ((unsigned)(d.y - lo) < PSIZE) csr[row_start[d.y] + rk.y] = s.y;
            if ((unsigned)(d.z - lo) < PSIZE) csr[row_start[d.z] + rk.z] = s.z;
            if ((unsigned)(d.w - lo) < PSIZE) csr[row_start[d.w] + rk.w] = s.w;
        }
    }
}

// ---------------- per-layer gather-max aggregation ----------------
// one wave per node; 16 lanes x float4 = one 256B row -> 4 neighbor rows per
// instruction; 4 independent csr loads + 4 independent row loads in flight
// per iteration (16 neighbors/iter; typical node = 1 iteration). Tail via
// index clamp (max is idempotent). Cross-group reduce via shfl_xor.
__global__ __launch_bounds__(256) void agg_kernel(const float* __restrict__ h,
                                                  const int* __restrict__ row_start,
                                                  const int* __restrict__ deg,
                                                  const int* __restrict__ csr,
                                                  float* __restrict__ agg) {
    int tid = threadIdx.x;
    int wv = tid >> 6;
    int lane = tid & 63;
    int g = lane >> 4;              // neighbor sub-slot 0..3
    int c4 = (lane & 15) * 4;       // column base
    int n = blockIdx.x * 4 + wv;    // NN = 25000*4 exactly
    int base = row_start[n];
    int cnt = deg[n];

    float4 acc;
    if (cnt > 0) {
        const float NI = -__builtin_huge_valf();
        acc = make_float4(NI, NI, NI, NI);
        int last = cnt - 1;
        for (int k = 0; k < cnt; k += 16) {
            int k0 = k + g;      if (k0 > last) k0 = last;
            int k1 = k + g + 4;  if (k1 > last) k1 = last;
            int k2 = k + g + 8;  if (k2 > last) k2 = last;
            int k3 = k + g + 12; if (k3 > last) k3 = last;
            int s0 = csr[base + k0];
            int s1 = csr[base + k1];
            int s2 = csr[base + k2];
            int s3 = csr[base + k3];
            float4 v0 = *(const float4*)&h[(size_t)s0 * DD + c4];
            float4 v1 = *(const float4*)&h[(size_t)s1 * DD + c4];
            float4 v2 = *(const float4*)&h[(size_t)s2 * DD + c4];
            float4 v3 = *(const float4*)&h[(size_t)s3 * DD + c4];
            acc.x = fmaxf(acc.x, fmaxf(fmaxf(v0.x, v1.x), fmaxf(v2.x, v3.x)));
            acc.y = fmaxf(acc.y, fmaxf(fmaxf(v0.y, v1.y), fmaxf(v2.y, v3.y)));
            acc.z = fmaxf(acc.z, fmaxf(fmaxf(v0.z, v1.z), fmaxf(v2.z, v3.z)));
            acc.w = fmaxf(acc.w, fmaxf(fmaxf(v0.w, v1.w), fmaxf(v2.w, v3.w)));
        }
        acc.x = fmaxf(acc.x, __shfl_xor(acc.x, 16, 64));
        acc.y = fmaxf(acc.y, __shfl_xor(acc.y, 16, 64));
        acc.z = fmaxf(acc.z, __shfl_xor(acc.z, 16, 64));
        acc.w = fmaxf(acc.w, __shfl_xor(acc.w, 16, 64));
        acc.x = fmaxf(acc.x, __shfl_xor(acc.x, 32, 64));
        acc.y = fmaxf(acc.y, __shfl_xor(acc.y, 32, 64));
        acc.z = fmaxf(acc.z, __shfl_xor(acc.z, 32, 64));
        acc.w = fmaxf(acc.w, __shfl_xor(acc.w, 32, 64));
    } else {
        acc = make_float4(0.f, 0.f, 0.f, 0.f);   // PyG empty-segment -> 0
    }
    if (lane < 16) *(float4*)&agg[(size_t)n * DD + c4] = acc;
}

// ---------------- dense update: h = relu(agg @ Wl + bl + h @ Wr), in place ----
__global__ __launch_bounds__(256, 2) void layer_kernel(const float* __restrict__ agg,
                                                       float* __restrict__ h,
                                                       const float* __restrict__ Wl,
                                                       const float* __restrict__ bl,
                                                       const float* __restrict__ Wr) {
    __shared__ float w_s[128 * DD];          // 32 KB: rows 0..63 = Wl, 64..127 = Wr
    __shared__ float a_t[KT * ASTRIDE];      // 16.5 KB: transposed k-tile of [agg|h]

    int tid = threadIdx.x;
    int ng = tid >> 3;        // 0..31 : node-group of 4
    int jg = tid & 7;         // 0..7  : output-group of 8
    int node0 = blockIdx.x * MB;

    #pragma unroll
    for (int r = 0; r < 8; ++r) {
        int idx = r * 256 + tid;
        int k = idx >> 4;
        int j4 = (idx & 15) * 4;
        const float* wsrc = (k < 64) ? (Wl + k * DD + j4) : (Wr + (k - 64) * DD + j4);
        *(float4*)&w_s[k * DD + j4] = *(const float4*)wsrc;
    }

    float acc[4][8];
    #pragma unroll
    for (int mi = 0; mi < 4; ++mi)
        #pragma unroll
        for (int ji = 0; ji < 8; ++ji) acc[mi][ji] = 0.0f;

    #pragma unroll
    for (int t = 0; t < 4; ++t) {
        __syncthreads();
        const float* smat = (t < 2) ? agg : h;
        int kbase = (t & 1) * KT;
        #pragma unroll
        for (int r = 0; r < 4; ++r) {
            int idx = r * 256 + tid;
            int ml = idx >> 3;
            int k4 = (idx & 7) * 4;
            int node = node0 + ml;
            if (node > NN - 1) node = NN - 1;
            float4 v = *(const float4*)&smat[(size_t)node * DD + kbase + k4];
            a_t[(k4 + 0) * ASTRIDE + ml] = v.x;
            a_t[(k4 + 1) * ASTRIDE + ml] = v.y;
            a_t[(k4 + 2) * ASTRIDE + ml] = v.z;
            a_t[(k4 + 3) * ASTRIDE + ml] = v.w;
        }
        __syncthreads();

        #pragma unroll 4
        for (int kk = 0; kk < KT; ++kk) {
            float4 av  = *(const float4*)&a_t[kk * ASTRIDE + ng * 4];
            float4 wv0 = *(const float4*)&w_s[(t * KT + kk) * DD + jg * 8];
            float4 wv1 = *(const float4*)&w_s[(t * KT + kk) * DD + jg * 8 + 4];
            float am[4] = {av.x, av.y, av.z, av.w};
            float wj[8] = {wv0.x, wv0.y, wv0.z, wv0.w, wv1.x, wv1.y, wv1.z, wv1.w};
            #pragma unroll
            for (int mi = 0; mi < 4; ++mi)
                #pragma unroll
                for (int ji = 0; ji < 8; ++ji)
                    acc[mi][ji] += am[mi] * wj[ji];
        }
    }

    float bj[8];
    #pragma unroll
    for (int ji = 0; ji < 8; ++ji) bj[ji] = bl[jg * 8 + ji];

    #pragma unroll
    for (int mi = 0; mi < 4; ++mi) {
        int node = node0 + ng * 4 + mi;
        if (node < NN) {
            float4 o0, o1;
            o0.x = fmaxf(acc[mi][0] + bj[0], 0.0f);
            o0.y = fmaxf(acc[mi][1] + bj[1], 0.0f);
            o0.z = fmaxf(acc[mi][2] + bj[2], 0.0f);
            o0.w = fmaxf(acc[mi][3] + bj[3], 0.0f);
            o1.x = fmaxf(acc[mi][4] + bj[4], 0.0f);
            o1.y = fmaxf(acc[mi][5] + bj[5], 0.0f);
            o1.z = fmaxf(acc[mi][6] + bj[6], 0.0f);
            o1.w = fmaxf(acc[mi][7] + bj[7], 0.0f);
            *(float4*)&h[(size_t)node * DD + jg * 8] = o0;
            *(float4*)&h[(size_t)node * DD + jg * 8 + 4] = o1;
        }
    }
}

extern "C" void kernel_launch(void* const* d_in, const int* in_sizes, int n_in,
                              void* d_out, int out_size, void* d_ws, size_t ws_size,
                              hipStream_t stream) {
    const float* x  = (const float*)d_in[0];
    const int*   ei = (const int*)d_in[1];
    const float* Wl = (const float*)d_in[2];
    const float* bl = (const float*)d_in[3];
    const float* Wr = (const float*)d_in[4];
    float* h = (float*)d_out;

    const int* src = ei;
    const int* dst = ei + NE;

    char* ws = (char*)d_ws;
    float* agg       = (float*)ws;                 ws += (size_t)NN * DD * sizeof(float); // 25.6 MB
    int*   row_start = (int*)ws;                   ws += (size_t)NN * sizeof(int);
    int*   deg       = (int*)ws;                   ws += (size_t)NN * sizeof(int);
    int*   blocksums = (int*)ws;                   ws += (size_t)128 * sizeof(int);
    int*   rank      = (int*)ws;                   ws += (size_t)NE * sizeof(int);       // 5 MB
    int*   csr       = (int*)ws;                                                          // 5 MB

    hipMemcpyAsync(h, x, (size_t)NN * DD * sizeof(float), hipMemcpyDeviceToDevice, stream);

    hipMemsetAsync(deg, 0, (size_t)NN * sizeof(int), stream);
    hist_kernel<<<(NE / 4 + 255) / 256, 256, 0, stream>>>(dst, deg, rank);
    scan1_kernel<<<SCAN_NB, SCAN_B, 0, stream>>>(deg, row_start, blocksums);
    scan2_kernel<<<1, 128, 0, stream>>>(blocksums);
    scan3_kernel<<<SCAN_NB, SCAN_B, 0, stream>>>(row_start, blocksums);
    fill_kernel<<<NCHUNK * NPART, 256, 0, stream>>>(src, dst, row_start, rank, csr);

    for (int l = 0; l < NL; ++l) {
        agg_kernel<<<NN / 4, 256, 0, stream>>>(h, row_start, deg, csr, agg);
        layer_kernel<<<LBLOCKS, 256, 0, stream>>>(
            agg, h, Wl + (size_t)l * DD * DD, bl + (size_t)l * DD, Wr + (size_t)l * DD * DD);
    }
}

// Round 6
// 461.702 us; speedup vs baseline: 10.0120x; 1.0467x over previous
//
#include <hip/hip_runtime.h>
#include <hip/hip_fp16.h>
#include <stdint.h>

#define NN 100000
#define NE 1250000
#define DD 64
#define NL 4
#define SCAN_B 1024
#define SCAN_NB ((NN + SCAN_B - 1) / SCAN_B)   // 98

#define MB 128               // nodes per layer-GEMM block
#define KT 32                // k-tile
#define ASTRIDE 132          // a_t row stride (multiple of 4, breaks pow2)
#define LBLOCKS ((NN + MB - 1) / MB)   // 782

#define NPART 8              // XCD partitions
#define PSIZE ((NN + NPART - 1) / NPART)          // 12500 dst nodes / partition
#define FCHUNK 1024          // int4s per chunk = 4096 edges
#define NCHUNK ((NE / 4 + FCHUNK - 1) / FCHUNK)   // 306

__device__ __forceinline__ float2 h2f2(unsigned u) {
    __half2 h = *reinterpret_cast<__half2*>(&u);
    return __half22float2(h);
}
__device__ __forceinline__ unsigned f2h2(float a, float b) {
    __half2 h = __floats2half2_rn(a, b);
    return *reinterpret_cast<unsigned*>(&h);
}

// ---- x (fp32) -> hh (fp16) ----
__global__ __launch_bounds__(256) void cast_kernel(const float* __restrict__ x,
                                                   __half* __restrict__ hh) {
    int i = blockIdx.x * 256 + threadIdx.x;        // float4 index; NN*DD/4 = 1.6M
    float4 v = ((const float4*)x)[i];
    uint2 u;
    u.x = f2h2(v.x, v.y);
    u.y = f2h2(v.z, v.w);
    ((uint2*)hh)[i] = u;
}

// ---------------- CSR build ----------------
// XCD-partitioned histogram: block b only counts dsts in partition (b&7), so
// deg atomics stay on one XCD's L2 lines. No rank store (the 44MB bounce).
__global__ __launch_bounds__(256) void hist_kernel(const int* __restrict__ dst,
                                                   int* __restrict__ deg) {
    int part = blockIdx.x & (NPART - 1);
    int chunk = blockIdx.x >> 3;
    unsigned lo = part * PSIZE;
    #pragma unroll
    for (int r = 0; r < 4; ++r) {
        int i4 = chunk * FCHUNK + r * 256 + threadIdx.x;
        if (i4 < NE / 4) {
            int4 d = ((const int4*)dst)[i4];
            if ((unsigned)(d.x - lo) < PSIZE) atomicAdd(&deg[d.x], 1);
            if ((unsigned)(d.y - lo) < PSIZE) atomicAdd(&deg[d.y], 1);
            if ((unsigned)(d.z - lo) < PSIZE) atomicAdd(&deg[d.z], 1);
            if ((unsigned)(d.w - lo) < PSIZE) atomicAdd(&deg[d.w], 1);
        }
    }
}

__global__ __launch_bounds__(SCAN_B) void scan1_kernel(const int* __restrict__ deg,
                                                       int* __restrict__ row_start,
                                                       int* __restrict__ blocksums) {
    __shared__ int sm[SCAN_B];
    int tid = threadIdx.x;
    int i = blockIdx.x * SCAN_B + tid;
    int d = (i < NN) ? deg[i] : 0;
    sm[tid] = d;
    __syncthreads();
    for (int off = 1; off < SCAN_B; off <<= 1) {
        int v = (tid >= off) ? sm[tid - off] : 0;
        __syncthreads();
        sm[tid] += v;
        __syncthreads();
    }
    if (i < NN) row_start[i] = sm[tid] - d;
    if (tid == SCAN_B - 1) blocksums[blockIdx.x] = sm[tid];
}

__global__ __launch_bounds__(128) void scan2_kernel(int* __restrict__ blocksums) {
    __shared__ int sm[128];
    int tid = threadIdx.x;
    int v = (tid < SCAN_NB) ? blocksums[tid] : 0;
    sm[tid] = v;
    __syncthreads();
    for (int off = 1; off < 128; off <<= 1) {
        int t = (tid >= off) ? sm[tid - off] : 0;
        __syncthreads();
        sm[tid] += t;
        __syncthreads();
    }
    if (tid < SCAN_NB) blocksums[tid] = sm[tid] - v;   // exclusive
}

__global__ __launch_bounds__(SCAN_B) void scan3_kernel(int* __restrict__ row_start,
                                                       const int* __restrict__ blocksums) {
    int i = blockIdx.x * SCAN_B + threadIdx.x;
    if (i < NN) row_start[i] += blocksums[blockIdx.x];
    if (blockIdx.x == 0 && threadIdx.x == 0) row_start[NN] = NE;
}

// XCD-partitioned fill; slot index from partition-local atomicSub countdown on
// deg (deg is consumed here; agg uses row_start[n+1]-row_start[n] instead).
__global__ __launch_bounds__(256) void fill_kernel(const int* __restrict__ src,
                                                   const int* __restrict__ dst,
                                                   const int* __restrict__ row_start,
                                                   int* __restrict__ deg,
                                                   int* __restrict__ csr) {
    int part = blockIdx.x & (NPART - 1);
    int chunk = blockIdx.x >> 3;
    unsigned lo = part * PSIZE;
    #pragma unroll
    for (int r = 0; r < 4; ++r) {
        int i4 = chunk * FCHUNK + r * 256 + threadIdx.x;
        if (i4 < NE / 4) {
            int4 d = ((const int4*)dst)[i4];
            int4 s = ((const int4*)src)[i4];
            int p;
            if ((unsigned)(d.x - lo) < PSIZE) { p = atomicSub(&deg[d.x], 1) - 1; csr[row_start[d.x] + p] = s.x; }
            if ((unsigned)(d.y - lo) < PSIZE) { p = atomicSub(&deg[d.y], 1) - 1; csr[row_start[d.y] + p] = s.y; }
            if ((unsigned)(d.z - lo) < PSIZE) { p = atomicSub(&deg[d.z], 1) - 1; csr[row_start[d.z] + p] = s.z; }
            if ((unsigned)(d.w - lo) < PSIZE) { p = atomicSub(&deg[d.w], 1) - 1; csr[row_start[d.w] + p] = s.w; }
        }
    }
}

// ---------------- per-layer gather-max (fp16 rows) ----------------
// one wave per node; 8-lane groups x 16B = one 128B fp16 row -> 8 neighbor
// rows per instruction, 16 per iteration. Tail via index clamp (max is
// idempotent). Cross-group reduce via shfl_xor 8/16/32. aggh output is fp16
// (exact: max of fp16 values).
__global__ __launch_bounds__(256) void agg_kernel(const __half* __restrict__ hh,
                                                  const int* __restrict__ row_start,
                                                  const int* __restrict__ csr,
                                                  __half* __restrict__ aggh) {
    int tid = threadIdx.x;
    int wv = tid >> 6;
    int lane = tid & 63;
    int g = lane >> 3;              // neighbor sub-slot 0..7
    int c8 = (lane & 7) * 8;        // column base (halfs)
    int n = blockIdx.x * 4 + wv;    // NN = 25000*4 exactly
    int base = row_start[n];
    int cnt = row_start[n + 1] - base;

    if (cnt > 0) {
        const float NI = -__builtin_huge_valf();
        float acc[8];
        #pragma unroll
        for (int i = 0; i < 8; ++i) acc[i] = NI;
        int last = cnt - 1;
        for (int k = 0; k < cnt; k += 16) {
            int k0 = k + g;     if (k0 > last) k0 = last;
            int k1 = k + g + 8; if (k1 > last) k1 = last;
            int s0 = csr[base + k0];
            int s1 = csr[base + k1];
            uint4 u0 = *(const uint4*)&hh[(size_t)s0 * DD + c8];
            uint4 u1 = *(const uint4*)&hh[(size_t)s1 * DD + c8];
            float2 p, q;
            p = h2f2(u0.x); q = h2f2(u1.x);
            acc[0] = fmaxf(acc[0], fmaxf(p.x, q.x));
            acc[1] = fmaxf(acc[1], fmaxf(p.y, q.y));
            p = h2f2(u0.y); q = h2f2(u1.y);
            acc[2] = fmaxf(acc[2], fmaxf(p.x, q.x));
            acc[3] = fmaxf(acc[3], fmaxf(p.y, q.y));
            p = h2f2(u0.z); q = h2f2(u1.z);
            acc[4] = fmaxf(acc[4], fmaxf(p.x, q.x));
            acc[5] = fmaxf(acc[5], fmaxf(p.y, q.y));
            p = h2f2(u0.w); q = h2f2(u1.w);
            acc[6] = fmaxf(acc[6], fmaxf(p.x, q.x));
            acc[7] = fmaxf(acc[7], fmaxf(p.y, q.y));
        }
        #pragma unroll
        for (int i = 0; i < 8; ++i) {
            acc[i] = fmaxf(acc[i], __shfl_xor(acc[i], 8, 64));
            acc[i] = fmaxf(acc[i], __shfl_xor(acc[i], 16, 64));
            acc[i] = fmaxf(acc[i], __shfl_xor(acc[i], 32, 64));
        }
        if (lane < 8) {
            uint4 u;
            u.x = f2h2(acc[0], acc[1]);
            u.y = f2h2(acc[2], acc[3]);
            u.z = f2h2(acc[4], acc[5]);
            u.w = f2h2(acc[6], acc[7]);
            *(uint4*)&aggh[(size_t)n * DD + lane * 8] = u;
        }
    } else {
        if (lane < 8) {
            uint4 z = make_uint4(0, 0, 0, 0);   // PyG empty-segment -> 0
            *(uint4*)&aggh[(size_t)n * DD + lane * 8] = z;
        }
    }
}

// ---------------- dense update ----------------
// hh_new = relu(aggh @ Wl + bl + hh @ Wr); fp32 result written to d_out only
// on the last layer. A-operands read fp16, compute fp32, W in LDS fp32.
__global__ __launch_bounds__(256, 2) void layer_kernel(const __half* __restrict__ aggh,
                                                       __half* __restrict__ hh,
                                                       float* __restrict__ hout,
                                                       const float* __restrict__ Wl,
                                                       const float* __restrict__ bl,
                                                       const float* __restrict__ Wr,
                                                       int last) {
    __shared__ float w_s[128 * DD];          // 32 KB: rows 0..63 = Wl, 64..127 = Wr
    __shared__ float a_t[KT * ASTRIDE];      // 16.5 KB: transposed k-tile of [agg|h]

    int tid = threadIdx.x;
    int ng = tid >> 3;        // 0..31 : node-group of 4
    int jg = tid & 7;         // 0..7  : output-group of 8
    int node0 = blockIdx.x * MB;

    #pragma unroll
    for (int r = 0; r < 8; ++r) {
        int idx = r * 256 + tid;
        int k = idx >> 4;
        int j4 = (idx & 15) * 4;
        const float* wsrc = (k < 64) ? (Wl + k * DD + j4) : (Wr + (k - 64) * DD + j4);
        *(float4*)&w_s[k * DD + j4] = *(const float4*)wsrc;
    }

    float acc[4][8];
    #pragma unroll
    for (int mi = 0; mi < 4; ++mi)
        #pragma unroll
        for (int ji = 0; ji < 8; ++ji) acc[mi][ji] = 0.0f;

    #pragma unroll
    for (int t = 0; t < 4; ++t) {
        __syncthreads();
        const __half* amat = (t < 2) ? aggh : hh;
        int kbase = (t & 1) * KT;
        #pragma unroll
        for (int r = 0; r < 4; ++r) {
            int idx = r * 256 + tid;
            int ml = idx >> 3;               // 0..127 local node
            int k4 = (idx & 7) * 4;
            int node = node0 + ml;
            if (node > NN - 1) node = NN - 1;   // clamp stays inside this block's range
            uint2 uv = *(const uint2*)&amat[(size_t)node * DD + kbase + k4];
            float2 f0 = h2f2(uv.x);
            float2 f1 = h2f2(uv.y);
            a_t[(k4 + 0) * ASTRIDE + ml] = f0.x;
            a_t[(k4 + 1) * ASTRIDE + ml] = f0.y;
            a_t[(k4 + 2) * ASTRIDE + ml] = f1.x;
            a_t[(k4 + 3) * ASTRIDE + ml] = f1.y;
        }
        __syncthreads();

        #pragma unroll 4
        for (int kk = 0; kk < KT; ++kk) {
            float4 av  = *(const float4*)&a_t[kk * ASTRIDE + ng * 4];
            float4 wv0 = *(const float4*)&w_s[(t * KT + kk) * DD + jg * 8];
            float4 wv1 = *(const float4*)&w_s[(t * KT + kk) * DD + jg * 8 + 4];
            float am[4] = {av.x, av.y, av.z, av.w};
            float wj[8] = {wv0.x, wv0.y, wv0.z, wv0.w, wv1.x, wv1.y, wv1.z, wv1.w};
            #pragma unroll
            for (int mi = 0; mi < 4; ++mi)
                #pragma unroll
                for (int ji = 0; ji < 8; ++ji)
                    acc[mi][ji] += am[mi] * wj[ji];
        }
    }

    float bj[8];
    #pragma unroll
    for (int ji = 0; ji < 8; ++ji) bj[ji] = bl[jg * 8 + ji];

    #pragma unroll
    for (int mi = 0; mi < 4; ++mi) {
        int node = node0 + ng * 4 + mi;
        if (node < NN) {
            float o[8];
            #pragma unroll
            for (int ji = 0; ji < 8; ++ji) o[ji] = fmaxf(acc[mi][ji] + bj[ji], 0.0f);
            uint4 u;
            u.x = f2h2(o[0], o[1]);
            u.y = f2h2(o[2], o[3]);
            u.z = f2h2(o[4], o[5]);
            u.w = f2h2(o[6], o[7]);
            *(uint4*)&hh[(size_t)node * DD + jg * 8] = u;
            if (last) {
                float4 o0 = make_float4(o[0], o[1], o[2], o[3]);
                float4 o1 = make_float4(o[4], o[5], o[6], o[7]);
                *(float4*)&hout[(size_t)node * DD + jg * 8] = o0;
                *(float4*)&hout[(size_t)node * DD + jg * 8 + 4] = o1;
            }
        }
    }
}

extern "C" void kernel_launch(void* const* d_in, const int* in_sizes, int n_in,
                              void* d_out, int out_size, void* d_ws, size_t ws_size,
                              hipStream_t stream) {
    const float* x  = (const float*)d_in[0];
    const int*   ei = (const int*)d_in[1];
    const float* Wl = (const float*)d_in[2];
    const float* bl = (const float*)d_in[3];
    const float* Wr = (const float*)d_in[4];
    float* h = (float*)d_out;

    const int* src = ei;
    const int* dst = ei + NE;

    char* ws = (char*)d_ws;
    __half* aggh     = (__half*)ws;  ws += (size_t)NN * DD * sizeof(__half);  // 12.8 MB
    __half* hh       = (__half*)ws;  ws += (size_t)NN * DD * sizeof(__half);  // 12.8 MB
    int* row_start   = (int*)ws;     ws += (size_t)(NN + 16) * sizeof(int);   // NN+1 used
    int* deg         = (int*)ws;     ws += (size_t)NN * sizeof(int);
    int* blocksums   = (int*)ws;     ws += 128 * sizeof(int);
    int* csr         = (int*)ws;                                              // 5 MB

    cast_kernel<<<(NN * DD / 4) / 256, 256, 0, stream>>>(x, hh);

    hipMemsetAsync(deg, 0, (size_t)NN * sizeof(int), stream);
    hist_kernel<<<NCHUNK * NPART, 256, 0, stream>>>(dst, deg);
    scan1_kernel<<<SCAN_NB, SCAN_B, 0, stream>>>(deg, row_start, blocksums);
    scan2_kernel<<<1, 128, 0, stream>>>(blocksums);
    scan3_kernel<<<SCAN_NB, SCAN_B, 0, stream>>>(row_start, blocksums);
    fill_kernel<<<NCHUNK * NPART, 256, 0, stream>>>(src, dst, row_start, deg, csr);

    for (int l = 0; l < NL; ++l) {
        agg_kernel<<<NN / 4, 256, 0, stream>>>(hh, row_start, csr, aggh);
        layer_kernel<<<LBLOCKS, 256, 0, stream>>>(
            aggh, hh, h, Wl + (size_t)l * DD * DD, bl + (size_t)l * DD, Wr + (size_t)l * DD * DD,
            (l == NL - 1) ? 1 : 0);
    }
}

// Round 8
// 409.588 us; speedup vs baseline: 11.2858x; 1.1272x over previous
//
#include <hip/hip_runtime.h>
#include <hip/hip_fp16.h>
#include <stdint.h>

#define NN 100000
#define NE 1250000
#define DD 64
#define NL 4
#define SCAN_B 1024
#define SCAN_NB ((NN + SCAN_B - 1) / SCAN_B)   // 98

#define NPART 8              // XCD partitions
#define PSIZE ((NN + NPART - 1) / NPART)          // 12500 dst nodes / partition
#define FCHUNK 1024          // int4s per chunk = 4096 edges
#define NCHUNK ((NE / 4 + FCHUNK - 1) / FCHUNK)   // 306

#define MB2 64               // nodes per MFMA layer block
#define L2BLOCKS ((NN + MB2 - 1) / MB2)   // 1563
#define APAD 136             // halfs per A/Bt LDS row (128+8; keeps b128 bank-balanced)
#define CPADH 72             // halfs per C row (16B-aligned rows)
#define CPADF 68             // floats per C row

typedef _Float16 half8 __attribute__((ext_vector_type(8)));
typedef float floatx4 __attribute__((ext_vector_type(4)));
typedef int intx4 __attribute__((ext_vector_type(4)));   // nt-load-compatible int4

__device__ __forceinline__ float2 h2f2(unsigned u) {
    __half2 h = *reinterpret_cast<__half2*>(&u);
    return __half22float2(h);
}
__device__ __forceinline__ unsigned f2h2(float a, float b) {
    __half2 h = __floats2half2_rn(a, b);
    return *reinterpret_cast<unsigned*>(&h);
}

// ---- x (fp32) -> hh (fp16) ----
__global__ __launch_bounds__(256) void cast_kernel(const float* __restrict__ x,
                                                   __half* __restrict__ hh) {
    int i = blockIdx.x * 256 + threadIdx.x;
    float4 v = ((const float4*)x)[i];
    uint2 u;
    u.x = f2h2(v.x, v.y);
    u.y = f2h2(v.z, v.w);
    ((uint2*)hh)[i] = u;
}

// ---------------- CSR build ----------------
// XCD-partitioned histogram; nt loads keep the 8x edge re-stream out of L2.
__global__ __launch_bounds__(256) void hist_kernel(const int* __restrict__ dst,
                                                   int* __restrict__ deg) {
    int part = blockIdx.x & (NPART - 1);
    int chunk = blockIdx.x >> 3;
    unsigned lo = part * PSIZE;
    #pragma unroll
    for (int r = 0; r < 4; ++r) {
        int i4 = chunk * FCHUNK + r * 256 + threadIdx.x;
        if (i4 < NE / 4) {
            intx4 d = __builtin_nontemporal_load(&((const intx4*)dst)[i4]);
            if ((unsigned)(d.x - lo) < PSIZE) atomicAdd(&deg[d.x], 1);
            if ((unsigned)(d.y - lo) < PSIZE) atomicAdd(&deg[d.y], 1);
            if ((unsigned)(d.z - lo) < PSIZE) atomicAdd(&deg[d.z], 1);
            if ((unsigned)(d.w - lo) < PSIZE) atomicAdd(&deg[d.w], 1);
        }
    }
}

__global__ __launch_bounds__(SCAN_B) void scan1_kernel(const int* __restrict__ deg,
                                                       int* __restrict__ row_start,
                                                       int* __restrict__ blocksums) {
    __shared__ int sm[SCAN_B];
    int tid = threadIdx.x;
    int i = blockIdx.x * SCAN_B + tid;
    int d = (i < NN) ? deg[i] : 0;
    sm[tid] = d;
    __syncthreads();
    for (int off = 1; off < SCAN_B; off <<= 1) {
        int v = (tid >= off) ? sm[tid - off] : 0;
        __syncthreads();
        sm[tid] += v;
        __syncthreads();
    }
    if (i < NN) row_start[i] = sm[tid] - d;
    if (tid == SCAN_B - 1) blocksums[blockIdx.x] = sm[tid];
}

__global__ __launch_bounds__(128) void scan2_kernel(int* __restrict__ blocksums) {
    __shared__ int sm[128];
    int tid = threadIdx.x;
    int v = (tid < SCAN_NB) ? blocksums[tid] : 0;
    sm[tid] = v;
    __syncthreads();
    for (int off = 1; off < 128; off <<= 1) {
        int t = (tid >= off) ? sm[tid - off] : 0;
        __syncthreads();
        sm[tid] += t;
        __syncthreads();
    }
    if (tid < SCAN_NB) blocksums[tid] = sm[tid] - v;   // exclusive
}

__global__ __launch_bounds__(SCAN_B) void scan3_kernel(int* __restrict__ row_start,
                                                       const int* __restrict__ blocksums) {
    int i = blockIdx.x * SCAN_B + threadIdx.x;
    if (i < NN) row_start[i] += blocksums[blockIdx.x];
    if (blockIdx.x == 0 && threadIdx.x == 0) row_start[NN] = NE;
}

// XCD-partitioned fill; nt loads for the edge stream; slot via partition-local
// atomicSub countdown on deg (deg consumed; agg uses row_start diffs).
__global__ __launch_bounds__(256) void fill_kernel(const int* __restrict__ src,
                                                   const int* __restrict__ dst,
                                                   const int* __restrict__ row_start,
                                                   int* __restrict__ deg,
                                                   int* __restrict__ csr) {
    int part = blockIdx.x & (NPART - 1);
    int chunk = blockIdx.x >> 3;
    unsigned lo = part * PSIZE;
    #pragma unroll
    for (int r = 0; r < 4; ++r) {
        int i4 = chunk * FCHUNK + r * 256 + threadIdx.x;
        if (i4 < NE / 4) {
            intx4 d = __builtin_nontemporal_load(&((const intx4*)dst)[i4]);
            intx4 s = __builtin_nontemporal_load(&((const intx4*)src)[i4]);
            int p;
            if ((unsigned)(d.x - lo) < PSIZE) { p = atomicSub(&deg[d.x], 1) - 1; csr[row_start[d.x] + p] = s.x; }
            if ((unsigned)(d.y - lo) < PSIZE) { p = atomicSub(&deg[d.y], 1) - 1; csr[row_start[d.y] + p] = s.y; }
            if ((unsigned)(d.z - lo) < PSIZE) { p = atomicSub(&deg[d.z], 1) - 1; csr[row_start[d.z] + p] = s.z; }
            if ((unsigned)(d.w - lo) < PSIZE) { p = atomicSub(&deg[d.w], 1) - 1; csr[row_start[d.w] + p] = s.w; }
        }
    }
}

// ---------------- per-layer gather-max (fp16 rows) ----------------
__global__ __launch_bounds__(256) void agg_kernel(const __half* __restrict__ hh,
                                                  const int* __restrict__ row_start,
                                                  const int* __restrict__ csr,
                                                  __half* __restrict__ aggh) {
    int tid = threadIdx.x;
    int wv = tid >> 6;
    int lane = tid & 63;
    int g = lane >> 3;              // neighbor sub-slot 0..7
    int c8 = (lane & 7) * 8;        // column base (halfs)
    int n = blockIdx.x * 4 + wv;    // NN = 25000*4 exactly
    int base = row_start[n];
    int cnt = row_start[n + 1] - base;

    if (cnt > 0) {
        const float NI = -__builtin_huge_valf();
        float acc[8];
        #pragma unroll
        for (int i = 0; i < 8; ++i) acc[i] = NI;
        int last = cnt - 1;
        for (int k = 0; k < cnt; k += 16) {
            int k0 = k + g;     if (k0 > last) k0 = last;
            int k1 = k + g + 8; if (k1 > last) k1 = last;
            int s0 = __builtin_nontemporal_load(&csr[base + k0]);
            int s1 = __builtin_nontemporal_load(&csr[base + k1]);
            uint4 u0 = *(const uint4*)&hh[(size_t)s0 * DD + c8];
            uint4 u1 = *(const uint4*)&hh[(size_t)s1 * DD + c8];
            float2 p, q;
            p = h2f2(u0.x); q = h2f2(u1.x);
            acc[0] = fmaxf(acc[0], fmaxf(p.x, q.x));
            acc[1] = fmaxf(acc[1], fmaxf(p.y, q.y));
            p = h2f2(u0.y); q = h2f2(u1.y);
            acc[2] = fmaxf(acc[2], fmaxf(p.x, q.x));
            acc[3] = fmaxf(acc[3], fmaxf(p.y, q.y));
            p = h2f2(u0.z); q = h2f2(u1.z);
            acc[4] = fmaxf(acc[4], fmaxf(p.x, q.x));
            acc[5] = fmaxf(acc[5], fmaxf(p.y, q.y));
            p = h2f2(u0.w); q = h2f2(u1.w);
            acc[6] = fmaxf(acc[6], fmaxf(p.x, q.x));
            acc[7] = fmaxf(acc[7], fmaxf(p.y, q.y));
        }
        #pragma unroll
        for (int i = 0; i < 8; ++i) {
            acc[i] = fmaxf(acc[i], __shfl_xor(acc[i], 8, 64));
            acc[i] = fmaxf(acc[i], __shfl_xor(acc[i], 16, 64));
            acc[i] = fmaxf(acc[i], __shfl_xor(acc[i], 32, 64));
        }
        if (lane < 8) {
            uint4 u;
            u.x = f2h2(acc[0], acc[1]);
            u.y = f2h2(acc[2], acc[3]);
            u.z = f2h2(acc[4], acc[5]);
            u.w = f2h2(acc[6], acc[7]);
            *(uint4*)&aggh[(size_t)n * DD + lane * 8] = u;
        }
    } else {
        if (lane < 8) {
            uint4 z = make_uint4(0, 0, 0, 0);   // PyG empty-segment -> 0
            *(uint4*)&aggh[(size_t)n * DD + lane * 8] = z;
        }
    }
}

// ---------------- dense update via MFMA ----------------
// hh_new = relu([aggh|hh] @ [Wl;Wr] + bl). 64 nodes/block, 4 waves; each wave
// computes a 16-node x 64-col strip with mfma_f32_16x16x32_f16 (fp32 accum).
// A/B frag layout: [m|n]=lane&15, k=(lane>>4)*8+j. C/D: col=lane&15,
// row=(lane>>4)*4+reg (m89-verified). Epilogue through LDS for coalesced out.
__global__ __launch_bounds__(256, 4) void layer_mfma_kernel(
        const __half* __restrict__ aggh,
        __half* __restrict__ hh,
        float* __restrict__ hout,
        const float* __restrict__ Wl,
        const float* __restrict__ bl,
        const float* __restrict__ Wr,
        int last) {
    __shared__ char smem[2 * MB2 * APAD * 2];   // 34816 B, reused by epilogue
    _Float16* a_s  = (_Float16*)smem;                          // [64][APAD]
    _Float16* bt_s = (_Float16*)(smem + MB2 * APAD * 2);       // [64][APAD], n-major

    int tid = threadIdx.x;
    int lane = tid & 63;
    int w = tid >> 6;
    int node0 = blockIdx.x * MB2;

    // stage A tile: row r = local node; halfs 0..63 = aggh row, 64..127 = hh row
    #pragma unroll
    for (int i = 0; i < 4; ++i) {
        int idx = i * 256 + tid;          // uint4 id, 1024 total
        int r = idx >> 4;
        int c4 = idx & 15;
        int node = node0 + r; if (node > NN - 1) node = NN - 1;
        const __half* srcp = (c4 < 8) ? (aggh + (size_t)node * DD + c4 * 8)
                                      : (hh + (size_t)node * DD + (c4 - 8) * 8);
        uint4 v = *(const uint4*)srcp;
        *(uint4*)&a_s[r * APAD + c4 * 8] = v;
    }
    // stage Bt[n][k] = (fp16) W[k][n], W = [Wl ; Wr]
    {
        int n = tid & 63;
        int kb = tid >> 6;
        #pragma unroll
        for (int kk = 0; kk < 32; ++kk) {
            int k = kb * 32 + kk;
            float wv = (k < 64) ? Wl[k * DD + n] : Wr[(k - 64) * DD + n];
            bt_s[n * APAD + k] = (_Float16)wv;
        }
    }
    __syncthreads();

    floatx4 acc[4];
    #pragma unroll
    for (int nt = 0; nt < 4; ++nt) acc[nt] = (floatx4){0.f, 0.f, 0.f, 0.f};
    int m = lane & 15;
    int q = lane >> 4;

    #pragma unroll
    for (int ks = 0; ks < 4; ++ks) {
        half8 af = *(half8*)&a_s[(w * 16 + m) * APAD + q * 8 + ks * 32];
        #pragma unroll
        for (int nt = 0; nt < 4; ++nt) {
            half8 bf = *(half8*)&bt_s[(nt * 16 + m) * APAD + q * 8 + ks * 32];
            acc[nt] = __builtin_amdgcn_mfma_f32_16x16x32_f16(af, bf, acc[nt], 0, 0, 0);
        }
    }
    __syncthreads();    // done with a_s/bt_s; reuse smem for epilogue

    _Float16* ch = (_Float16*)smem;                      // [64][CPADH] halfs (9216 B)
    float*    cf = (float*)(smem + MB2 * CPADH * 2);     // [64][CPADF] floats (17408 B)

    #pragma unroll
    for (int nt = 0; nt < 4; ++nt) {
        int col = nt * 16 + m;
        float b = bl[col];
        #pragma unroll
        for (int r = 0; r < 4; ++r) {
            int rowl = w * 16 + q * 4 + r;
            float o = fmaxf(acc[nt][r] + b, 0.0f);
            ch[rowl * CPADH + col] = (_Float16)o;
            if (last) cf[rowl * CPADF + col] = o;
        }
    }
    __syncthreads();

    // coalesced fp16 store of the whole 64x64 tile
    #pragma unroll
    for (int i = 0; i < 2; ++i) {
        int idx = i * 256 + tid;          // 512 uint4s
        int r = idx >> 3;
        int c4 = idx & 7;
        int node = node0 + r;
        if (node < NN) {
            uint4 v = *(uint4*)&ch[r * CPADH + c4 * 8];
            *(uint4*)&hh[(size_t)node * DD + c4 * 8] = v;
        }
    }
    if (last) {
        #pragma unroll
        for (int i = 0; i < 4; ++i) {
            int idx = i * 256 + tid;      // 1024 float4s
            int r = idx >> 4;
            int c4 = idx & 15;
            int node = node0 + r;
            if (node < NN) {
                float4 v = *(float4*)&cf[r * CPADF + c4 * 4];
                *(float4*)&hout[(size_t)node * DD + c4 * 4] = v;
            }
        }
    }
}

extern "C" void kernel_launch(void* const* d_in, const int* in_sizes, int n_in,
                              void* d_out, int out_size, void* d_ws, size_t ws_size,
                              hipStream_t stream) {
    const float* x  = (const float*)d_in[0];
    const int*   ei = (const int*)d_in[1];
    const float* Wl = (const float*)d_in[2];
    const float* bl = (const float*)d_in[3];
    const float* Wr = (const float*)d_in[4];
    float* h = (float*)d_out;

    const int* src = ei;
    const int* dst = ei + NE;

    char* ws = (char*)d_ws;
    __half* aggh     = (__half*)ws;  ws += (size_t)NN * DD * sizeof(__half);  // 12.8 MB
    __half* hh       = (__half*)ws;  ws += (size_t)NN * DD * sizeof(__half);  // 12.8 MB
    int* row_start   = (int*)ws;     ws += (size_t)(NN + 16) * sizeof(int);
    int* deg         = (int*)ws;     ws += (size_t)NN * sizeof(int);
    int* blocksums   = (int*)ws;     ws += 128 * sizeof(int);
    int* csr         = (int*)ws;                                              // 5 MB

    cast_kernel<<<(NN * DD / 4) / 256, 256, 0, stream>>>(x, hh);

    hipMemsetAsync(deg, 0, (size_t)NN * sizeof(int), stream);
    hist_kernel<<<NCHUNK * NPART, 256, 0, stream>>>(dst, deg);
    scan1_kernel<<<SCAN_NB, SCAN_B, 0, stream>>>(deg, row_start, blocksums);
    scan2_kernel<<<1, 128, 0, stream>>>(blocksums);
    scan3_kernel<<<SCAN_NB, SCAN_B, 0, stream>>>(row_start, blocksums);
    fill_kernel<<<NCHUNK * NPART, 256, 0, stream>>>(src, dst, row_start, deg, csr);

    for (int l = 0; l < NL; ++l) {
        agg_kernel<<<NN / 4, 256, 0, stream>>>(hh, row_start, csr, aggh);
        layer_mfma_kernel<<<L2BLOCKS, 256, 0, stream>>>(
            aggh, hh, h, Wl + (size_t)l * DD * DD, bl + (size_t)l * DD, Wr + (size_t)l * DD * DD,
            (l == NL - 1) ? 1 : 0);
    }
}